// Round 1
// baseline (88.425 us; speedup 1.0000x reference)
//
#include <hip/hip_runtime.h>

// Problem constants
#define LSEQ 256   // sequence length (i, j range)
#define INC  256   // in_channels
#define HID  32    // hidden_dim
#define OUTC 32    // out_channels
#define DE   1024  // HID*HID (LayerNorm width)
#define EPSV 1e-5f

// ---------------------------------------------------------------------------
// k1: blocks 0..31  -> a[i,d] = x[i,:]@W1[:,d] + b1[d]; S_i = sum_d a; Q_i = sum_d a^2
//     block  32     -> GW[o] = sum_de gamma*W2 ; C[o] = sum_de beta*W2 + b2[o]
// ---------------------------------------------------------------------------
__global__ __launch_bounds__(256) void k1_a_stats(
    const float* __restrict__ x, const float* __restrict__ W1, const float* __restrict__ b1,
    const float* __restrict__ gamma, const float* __restrict__ beta,
    const float* __restrict__ W2, const float* __restrict__ b2,
    float* __restrict__ a, float* __restrict__ S, float* __restrict__ Q,
    float* __restrict__ GW, float* __restrict__ C)
{
    __shared__ float sh0[256];
    __shared__ float sh1[256];
    const int t = threadIdx.x;
    const int b = blockIdx.x;
    if (b < 32) {
        const int i = b * 8 + (t >> 5);   // 8 rows per block
        const int d = t & 31;
        const float* xr = x + i * INC;
        float acc = b1[d];
        #pragma unroll 8
        for (int c = 0; c < INC; ++c)
            acc = fmaf(xr[c], W1[c * HID + d], acc);   // xr[c]: broadcast; W1: coalesced over d
        a[i * HID + d] = acc;
        sh0[t] = acc;
        sh1[t] = acc * acc;
        __syncthreads();
        if (t < 8) {
            float s = 0.f, q = 0.f;
            #pragma unroll
            for (int d2 = 0; d2 < 32; ++d2) { s += sh0[t * 32 + d2]; q += sh1[t * 32 + d2]; }
            S[b * 8 + t] = s;
            Q[b * 8 + t] = q;
        }
    } else {
        // constants: per-o sums over the 1024 LayerNorm lanes
        const int o = t & 31, chunk = t >> 5;   // 8 chunks x 128 de each
        float gw = 0.f, bw = 0.f;
        for (int k = 0; k < 128; ++k) {
            const int de = chunk * 128 + k;
            const float w = W2[de * OUTC + o];  // coalesced over o
            gw = fmaf(gamma[de], w, gw);
            bw = fmaf(beta[de],  w, bw);
        }
        sh0[t] = gw; sh1[t] = bw;
        __syncthreads();
        if (t < 32) {
            float g = 0.f, bb = 0.f;
            #pragma unroll
            for (int c2 = 0; c2 < 8; ++c2) { g += sh0[c2 * 32 + t]; bb += sh1[c2 * 32 + t]; }
            GW[t] = g;
            C[t]  = bb + b2[t];
        }
    }
}

// ---------------------------------------------------------------------------
// k2: T[j,d,o] = sum_e a[j,e] * gamma[d*32+e] * W2[(d*32+e)*32 + o]
// one block per j, 1024 threads (thread = d*32+o)
// ---------------------------------------------------------------------------
__global__ __launch_bounds__(1024) void k2_T(
    const float* __restrict__ a, const float* __restrict__ gamma,
    const float* __restrict__ W2, float* __restrict__ T)
{
    const int j = blockIdx.x, t = threadIdx.x;
    __shared__ float aj[HID];
    if (t < HID) aj[t] = a[j * HID + t];
    __syncthreads();
    const int d = t >> 5, o = t & 31;
    float acc = 0.f;
    #pragma unroll
    for (int e = 0; e < 32; ++e) {
        const int de = d * 32 + e;
        acc = fmaf(aj[e] * gamma[de], W2[de * OUTC + o], acc);  // W2 coalesced over o
    }
    T[j * DE + t] = acc;
}

// ---------------------------------------------------------------------------
// k3: out[i,j,o] = r_ij * ( sum_d a[i,d]*T[j,d,o] - mu_ij*GW[o] ) + C[o]
//     mu = S_i*S_j/1024 ; var = Q_i*Q_j/1024 - mu^2 ; r = rsqrt(var+eps)
// one block per j, 256 threads; thread = (i-subrow 0..7, o 0..31), 32 passes over i
// ---------------------------------------------------------------------------
__global__ __launch_bounds__(256) void k3_out(
    const float* __restrict__ a, const float* __restrict__ S, const float* __restrict__ Q,
    const float* __restrict__ GW, const float* __restrict__ C,
    const float* __restrict__ T, float* __restrict__ out)
{
    const int j = blockIdx.x, t = threadIdx.x;
    __shared__ float aL[LSEQ * HID];   // 32 KB: all of a
    __shared__ float tL[DE];           // 4 KB: T_j
    __shared__ float sL[LSEQ];         // 1 KB
    __shared__ float qL[LSEQ];         // 1 KB
    __shared__ float gwL[OUTC], cL[OUTC];

    for (int k = t; k < LSEQ * HID; k += 256) aL[k] = a[k];
    for (int k = t; k < DE; k += 256)         tL[k] = T[j * DE + k];
    sL[t] = S[t];
    qL[t] = Q[t];
    if (t < OUTC) { gwL[t] = GW[t]; cL[t] = C[t]; }
    __syncthreads();

    const int o  = t & 31;
    const int i0 = t >> 5;            // 8 i-values per pass
    const float Sj = sL[j], Qj = qL[j];
    const float gw = gwL[o], cc = cL[o];

    for (int rep = 0; rep < 32; ++rep) {
        const int i = rep * 8 + i0;
        float acc = 0.f;
        #pragma unroll
        for (int d = 0; d < 32; ++d)
            acc = fmaf(aL[i * HID + d], tL[d * 32 + o], acc);  // aL: broadcast; tL: conflict-free
        const float Si = sL[i], Qi = qL[i];
        const float mu  = Si * Sj * (1.0f / 1024.0f);
        const float ex2 = Qi * Qj * (1.0f / 1024.0f);
        const float var = ex2 - mu * mu;
        const float r   = rsqrtf(var + EPSV);
        out[(i * LSEQ + j) * OUTC + o] = r * (acc - mu * gw) + cc;
    }
}

// ---------------------------------------------------------------------------
extern "C" void kernel_launch(void* const* d_in, const int* in_sizes, int n_in,
                              void* d_out, int out_size, void* d_ws, size_t ws_size,
                              hipStream_t stream)
{
    const float* x     = (const float*)d_in[0];
    const float* W1    = (const float*)d_in[1];
    const float* b1    = (const float*)d_in[2];
    const float* gamma = (const float*)d_in[3];
    const float* beta  = (const float*)d_in[4];
    const float* W2    = (const float*)d_in[5];
    const float* b2    = (const float*)d_in[6];
    float* out = (float*)d_out;

    // workspace layout (floats)
    float* ws = (float*)d_ws;
    float* a  = ws;            // 8192
    float* S  = ws + 8192;     // 256
    float* Q  = ws + 8448;     // 256
    float* GW = ws + 8704;     // 32
    float* C  = ws + 8736;     // 32
    float* T  = ws + 8768;     // 262144

    k1_a_stats<<<33, 256, 0, stream>>>(x, W1, b1, gamma, beta, W2, b2, a, S, Q, GW, C);
    k2_T<<<LSEQ, 1024, 0, stream>>>(a, gamma, W2, T);
    k3_out<<<LSEQ, 256, 0, stream>>>(a, S, Q, GW, C, T, out);
}

// Round 2
// 80.649 us; speedup vs baseline: 1.0964x; 1.0964x over previous
//
#include <hip/hip_runtime.h>

// Problem constants
#define LSEQ 256   // sequence length (i, j range)
#define INC  256   // in_channels
#define HID  32    // hidden_dim
#define OUTC 32    // out_channels
#define DE   1024  // HID*HID (LayerNorm width)
#define EPSV 1e-5f

// aPad layout: a[i][d] stored at aPad[(i>>3)*ASTR + d*8 + (i&7)]
//  - chunk stride 260 floats (1040 B, 16B-aligned); 260%32==4 so GEMM-phase
//    float4 reads across iT lanes are bandwidth-optimal (banks 4*iT+8d+k, all
//    32 banks hit, 8 distinct addrs/wave -> broadcast across oT).
#define ASTR 260
// tPad layout: T[d][o] at tPad[d*TSTR + o]; 36%32==4 -> GEMM reads conflict-free,
// 36*4=144 B keeps float4 alignment.
#define TSTR 36

// ---------------------------------------------------------------------------
// k1: blocks 0..63 -> 4 rows each of a[i,d]=x[i,:]@W1[:,d]+b1[d], plus S_i,Q_i
//     block  64    -> GW[o]=sum_de gamma*W2 ; C[o]=sum_de beta*W2 + b2[o]
// thread (b<64): r=t>>6 (row 0..3), h=(t>>5)&1 (c-half), d=t&31
// ---------------------------------------------------------------------------
__global__ __launch_bounds__(256) void k1_a_stats(
    const float* __restrict__ x, const float* __restrict__ W1, const float* __restrict__ b1,
    const float* __restrict__ gamma, const float* __restrict__ beta,
    const float* __restrict__ W2, const float* __restrict__ b2,
    float* __restrict__ a, float* __restrict__ S, float* __restrict__ Q,
    float* __restrict__ GW, float* __restrict__ C)
{
    __shared__ float sh0[256];
    __shared__ float sh1[256];
    __shared__ float shA[128];
    __shared__ float shB[128];
    const int t = threadIdx.x;
    const int b = blockIdx.x;
    if (b < 64) {
        const int r = t >> 6;
        const int h = (t >> 5) & 1;
        const int d = t & 31;
        const int i = b * 4 + r;
        const float* xr = x + i * INC + h * 128;
        const float* w  = W1 + (h * 128) * HID + d;
        float p0 = 0.f, p1 = 0.f;                 // 2 independent chains
        #pragma unroll 8
        for (int k = 0; k < 64; ++k) {
            p0 = fmaf(xr[2 * k],     w[(2 * k) * HID],     p0);
            p1 = fmaf(xr[2 * k + 1], w[(2 * k + 1) * HID], p1);
        }
        sh0[t] = p0 + p1;
        __syncthreads();
        if (h == 0) {
            const float tot = sh0[t] + sh0[t + 32] + b1[d];
            a[i * HID + d] = tot;
            shA[r * 32 + d] = tot;
            shB[r * 32 + d] = tot * tot;
        }
        __syncthreads();
        if (t < 4) {
            float s = 0.f, q = 0.f;
            #pragma unroll
            for (int d2 = 0; d2 < 32; ++d2) { s += shA[t * 32 + d2]; q += shB[t * 32 + d2]; }
            S[b * 4 + t] = s;
            Q[b * 4 + t] = q;
        }
    } else {
        // constants: per-o sums over the 1024 LayerNorm lanes
        const int o = t & 31, chunk = t >> 5;     // 8 chunks x 128 de each
        float gw = 0.f, bw = 0.f;
        for (int k = 0; k < 128; ++k) {
            const int de = chunk * 128 + k;
            const float w = W2[de * OUTC + o];    // coalesced over o
            gw = fmaf(gamma[de], w, gw);
            bw = fmaf(beta[de],  w, bw);
        }
        sh0[t] = gw; sh1[t] = bw;
        __syncthreads();
        if (t < 32) {
            float g = 0.f, bb = 0.f;
            #pragma unroll
            for (int c2 = 0; c2 < 8; ++c2) { g += sh0[c2 * 32 + t]; bb += sh1[c2 * 32 + t]; }
            GW[t] = g;
            C[t]  = bb + b2[t];
        }
    }
}

// ---------------------------------------------------------------------------
// k2: fused per-j kernel. One block per j, 256 threads.
//   phase 0: stage a (chunked-transposed), S, Q, GW, C, gamma into LDS
//   phase 1: T_j[d][o] = sum_e a[j,e]*gamma[d*32+e]*W2[(d*32+e)*32+o]
//   phase 2: reg-tiled GEMM: thread (iT=t>>3, oT=t&7) owns 8i x 4o tile
//            out[i,j,o] = r_ij*(sum_d a[i,d]*T[d,o] - mu_ij*GW[o]) + C[o]
// ---------------------------------------------------------------------------
__global__ __launch_bounds__(256) void k2_fused(
    const float* __restrict__ a, const float* __restrict__ S, const float* __restrict__ Q,
    const float* __restrict__ GW, const float* __restrict__ C,
    const float* __restrict__ gamma, const float* __restrict__ W2,
    float* __restrict__ out)
{
    const int j = blockIdx.x, t = threadIdx.x;
    __shared__ float aPad[32 * ASTR];   // 33.3 KB
    __shared__ float tPad[32 * TSTR];   // 4.6 KB
    __shared__ float gL[DE];            // 4 KB
    __shared__ float sL[LSEQ];
    __shared__ float qL[LSEQ];
    __shared__ float gwL[OUTC], cL[OUTC];

    // ---- phase 0: stage ----
    {   // thread t owns row i=t of a: 8 float4 global reads (L2-hot), scatter to aPad
        const float4* ar4 = (const float4*)(a + t * HID);
        const int base = (t >> 3) * ASTR + (t & 7);
        #pragma unroll
        for (int c = 0; c < 8; ++c) {
            const float4 v = ar4[c];
            const int d = c * 4;
            aPad[base + (d + 0) * 8] = v.x;
            aPad[base + (d + 1) * 8] = v.y;
            aPad[base + (d + 2) * 8] = v.z;
            aPad[base + (d + 3) * 8] = v.w;
        }
    }
    #pragma unroll
    for (int k = t; k < DE; k += 256) gL[k] = gamma[k];
    sL[t] = S[t];
    qL[t] = Q[t];
    if (t < OUTC) { gwL[t] = GW[t]; cL[t] = C[t]; }
    __syncthreads();

    // ---- phase 1: T_j ----
    {
        const int d = t >> 3, o0 = (t & 7) * 4;
        const int jb = (j >> 3) * ASTR + (j & 7);
        float4 acc = {0.f, 0.f, 0.f, 0.f};
        #pragma unroll
        for (int e = 0; e < 32; ++e) {
            const float g = gL[d * 32 + e] * aPad[jb + e * 8];
            const float4 w = *(const float4*)(W2 + (d * 32 + e) * OUTC + o0);
            acc.x = fmaf(g, w.x, acc.x);
            acc.y = fmaf(g, w.y, acc.y);
            acc.z = fmaf(g, w.z, acc.z);
            acc.w = fmaf(g, w.w, acc.w);
        }
        *(float4*)(tPad + d * TSTR + o0) = acc;
    }
    __syncthreads();

    // ---- phase 2: reg-tiled GEMM + LN epilogue ----
    const int iT = t >> 3, oT = t & 7;
    const int abase = iT * ASTR;
    float acc[8][4];
    #pragma unroll
    for (int m = 0; m < 8; ++m)
        #pragma unroll
        for (int k = 0; k < 4; ++k) acc[m][k] = 0.f;

    #pragma unroll
    for (int d = 0; d < 32; ++d) {
        const float4 a0 = *(const float4*)(aPad + abase + d * 8);
        const float4 a1 = *(const float4*)(aPad + abase + d * 8 + 4);
        const float4 tf = *(const float4*)(tPad + d * TSTR + oT * 4);
        const float am[8] = {a0.x, a0.y, a0.z, a0.w, a1.x, a1.y, a1.z, a1.w};
        const float tk[4] = {tf.x, tf.y, tf.z, tf.w};
        #pragma unroll
        for (int m = 0; m < 8; ++m)
            #pragma unroll
            for (int k = 0; k < 4; ++k)
                acc[m][k] = fmaf(am[m], tk[k], acc[m][k]);
    }

    const float Sj = sL[j], Qj = qL[j];
    const float gw0 = gwL[oT * 4 + 0], gw1 = gwL[oT * 4 + 1];
    const float gw2 = gwL[oT * 4 + 2], gw3 = gwL[oT * 4 + 3];
    const float c0 = cL[oT * 4 + 0], c1 = cL[oT * 4 + 1];
    const float c2 = cL[oT * 4 + 2], c3 = cL[oT * 4 + 3];

    #pragma unroll
    for (int m = 0; m < 8; ++m) {
        const int i = iT * 8 + m;
        const float Si = sL[i], Qi = qL[i];
        const float mu  = Si * Sj * (1.0f / 1024.0f);
        const float ex2 = Qi * Qj * (1.0f / 1024.0f);
        const float var = ex2 - mu * mu;
        const float r   = rsqrtf(var + EPSV);
        float4 o4;
        o4.x = fmaf(r, acc[m][0] - mu * gw0, c0);
        o4.y = fmaf(r, acc[m][1] - mu * gw1, c1);
        o4.z = fmaf(r, acc[m][2] - mu * gw2, c2);
        o4.w = fmaf(r, acc[m][3] - mu * gw3, c3);
        // 8 consecutive lanes (oT=0..7) cover one full 128 B row (i,j,:)
        *(float4*)(out + (i * LSEQ + j) * OUTC + oT * 4) = o4;
    }
}

// ---------------------------------------------------------------------------
extern "C" void kernel_launch(void* const* d_in, const int* in_sizes, int n_in,
                              void* d_out, int out_size, void* d_ws, size_t ws_size,
                              hipStream_t stream)
{
    const float* x     = (const float*)d_in[0];
    const float* W1    = (const float*)d_in[1];
    const float* b1    = (const float*)d_in[2];
    const float* gamma = (const float*)d_in[3];
    const float* beta  = (const float*)d_in[4];
    const float* W2    = (const float*)d_in[5];
    const float* b2    = (const float*)d_in[6];
    float* out = (float*)d_out;

    // workspace layout (floats)
    float* ws = (float*)d_ws;
    float* a  = ws;            // 8192
    float* S  = ws + 8192;     // 256
    float* Q  = ws + 8448;     // 256
    float* GW = ws + 8704;     // 32
    float* C  = ws + 8736;     // 32

    k1_a_stats<<<65, 256, 0, stream>>>(x, W1, b1, gamma, beta, W2, b2, a, S, Q, GW, C);
    k2_fused<<<LSEQ, 256, 0, stream>>>(a, S, Q, GW, C, gamma, W2, out);
}